// Round 7
// baseline (135.318 us; speedup 1.0000x reference)
//
#include <hip/hip_runtime.h>

// Problem constants: BS=2048, P=32, C=14
constexpr int NB = 2048;
constexpr int NP = 32;
constexpr int NC = 14;
constexpr int ELEMS_PER_B = NP * NP * NC;   // 14336 floats per batch slice
constexpr int NT = 448;                      // 7 waves
constexpr int NITER = 8;                     // 448 threads * 4 floats * 8 iters = 14336

typedef float f32x4 __attribute__((ext_vector_type(4)));  // builtin-friendly vec4

// Flat element f = it*1792 + 4*tid + k  (1792 = 14*128, channel-neutral per iter)
//   ch      = (4*tid+k) % 14      (constant per thread/k)
//   posBase = (4*tid+k) / 14      in [0,128)
//   pos     = it*128 + posBase ;  j = posBase&31 (const) ; i = 4*it + (posBase>>5)
// (ch, posBase) is a bijection over the 1792 thread-lane slots -> LDS [14][128] reduction.
__global__ __launch_bounds__(NT) void loss_main(
    const float* __restrict__ y_pred,
    const float* __restrict__ eta,
    const float* __restrict__ p_in,
    const float* __restrict__ bbox,
    float* __restrict__ partial,
    unsigned* __restrict__ cnt,   // zeroed by hipMemsetAsync at every launch
    float* __restrict__ out)
{
    const int b   = blockIdx.x;
    const int tid = threadIdx.x;

    __shared__ int      win[NC][4];          // x0, y0, x1, y1
    __shared__ float    ep[2][NC];           // eta, p (prefetched early)
    __shared__ float    rAll[NC * 128];
    __shared__ float    r1[NC * 128];
    __shared__ float    r3[NC * 128];
    __shared__ float    lossArr[NC];
    __shared__ float    waveSumF[7];
    __shared__ unsigned isLastSh;

    if (tid < NC) {
        const float* bb = bbox + ((size_t)b * NC + tid) * 4;
        int x0 = (int)(bb[0] * (float)NP);   // trunc toward zero == astype(int32)
        int y0 = (int)(bb[1] * (float)NP);
        int w  = (int)(bb[2] * (float)NP);
        int h  = (int)(bb[3] * (float)NP);
        win[tid][0] = x0;
        win[tid][1] = y0;
        win[tid][2] = x0 + w;
        win[tid][3] = y0 + h;
        ep[0][tid] = eta[(size_t)b * NC + tid];
        ep[1][tid] = p_in[(size_t)b * NC + tid];
    }
    __syncthreads();

    int  ch[4], pB[4], ihi[4], ry0[4], ry1[4];
    bool col[4];
    #pragma unroll
    for (int k = 0; k < 4; ++k) {
        int f0 = 4 * tid + k;
        ch[k]  = f0 % NC;
        pB[k]  = f0 / NC;
        int j  = pB[k] & 31;
        ihi[k] = pB[k] >> 5;
        ry0[k] = win[ch[k]][1];
        ry1[k] = win[ch[k]][3];
        col[k] = (j >= win[ch[k]][0]) && (j < win[ch[k]][2]);
    }

    float aAll[4] = {1.f, 1.f, 1.f, 1.f};
    float a1[4]   = {1.f, 1.f, 1.f, 1.f};
    float a3[4]   = {1.f, 1.f, 1.f, 1.f};

    const f32x4* base = reinterpret_cast<const f32x4*>(y_pred + (size_t)b * ELEMS_PER_B);

    #pragma unroll
    for (int it = 0; it < NITER; ++it) {
        const f32x4 v = __builtin_nontemporal_load(base + it * NT + tid);
        #pragma unroll
        for (int k = 0; k < 4; ++k) {
            const int i = 4 * it + ihi[k];
            float yp0 = fminf(1.f, v[k]);
            float t0  = fminf(1.f, 1.f - yp0);
            float yp  = fmaf(yp0, 0.02f, 0.98f);
            float t   = fmaf(t0,  0.02f, 0.98f);
            aAll[k] *= t;
            bool m = col[k] && (i >= ry0[k]) && (i < ry1[k]);
            a1[k] *= m ? yp : 1.f;
            a3[k] *= m ? t  : 1.f;
        }
    }

    #pragma unroll
    for (int k = 0; k < 4; ++k) {
        const int a = ch[k] * 128 + pB[k];
        rAll[a] = aAll[k];
        r1[a]   = a1[k];
        r3[a]   = a3[k];
    }
    __syncthreads();

    // 7-step multiply tree over the 128 partials per channel
    #pragma unroll
    for (int s = 64; s >= 1; s >>= 1) {
        for (int idx = tid; idx < NC * s; idx += NT) {
            const int c = idx / s, m = idx - c * s;
            const int a = c * 128 + m, a2 = a + s;
            rAll[a] *= rAll[a2];
            r1[a]   *= r1[a2];
            r3[a]   *= r3[a2];
        }
        __syncthreads();
    }

    if (tid < NC) {
        float Pall = rAll[tid * 128];        // prod of tmp over all (i,j)
        float P1   = r1[tid * 128];          // prod of yp inside bbox
        float P3   = r3[tid * 128];          // prod of tmp inside bbox
        float pyx  = 1.f - Pall;
        float pyxb = P1 * Pall / P3 + 1e-10f;
        float e  = ep[0][tid];
        float pp = ep[1][tid];
        float loss = -e * logf(pyxb)
                     - (1.f - e) * pp * logf(pyx)
                     - (1.f - e) * (1.f - pp) * logf(Pall);
        lossArr[tid] = loss;
    }
    __syncthreads();

    if (tid == 0) {
        float s = 0.f;
        #pragma unroll
        for (int c = 0; c < NC; ++c) s += lossArr[c];
        // Publish this block's partial (distinct address -> no contention), then
        // bump the arrival counter. Counter starts at 0 every launch (memset in
        // the same graph), so old == NB-1 identifies the true last arrival.
        __hip_atomic_store(&partial[b], s, __ATOMIC_RELEASE, __HIP_MEMORY_SCOPE_AGENT);
        unsigned old = __hip_atomic_fetch_add(cnt, 1u, __ATOMIC_ACQ_REL, __HIP_MEMORY_SCOPE_AGENT);
        isLastSh = (old == (unsigned)(NB - 1)) ? 1u : 0u;
    }
    __syncthreads();

    if (isLastSh) {
        // Last-arriving block: all 2048 partials are published (their release
        // stores happened-before our acquiring RMW). Fixed-order re-read +
        // reduction -> bitwise-deterministic output regardless of which block
        // executes this.
        float acc = 0.f;
        for (int i = tid; i < NB; i += NT)
            acc += __hip_atomic_load(&partial[i], __ATOMIC_RELAXED, __HIP_MEMORY_SCOPE_AGENT);
        #pragma unroll
        for (int off = 32; off >= 1; off >>= 1)
            acc += __shfl_xor(acc, off);
        if ((tid & 63) == 0) waveSumF[tid >> 6] = acc;
        __syncthreads();
        if (tid == 0) {
            float s = 0.f;
            #pragma unroll
            for (int i = 0; i < 7; ++i) s += waveSumF[i];
            out[0] = s * (1.0f / (float)NB);
        }
    }
}

extern "C" void kernel_launch(void* const* d_in, const int* in_sizes, int n_in,
                              void* d_out, int out_size, void* d_ws, size_t ws_size,
                              hipStream_t stream)
{
    const float* y_pred = (const float*)d_in[0];
    const float* eta    = (const float*)d_in[1];
    const float* p_in   = (const float*)d_in[2];
    const float* bbox   = (const float*)d_in[3];
    float*    partial = (float*)d_ws;                 // 2048 floats
    unsigned* cnt     = (unsigned*)(partial + NB);    // arrival counter
    float*    out     = (float*)d_out;

    // Counter must be 0 at the start of every launch (d_ws is poisoned to 0xAA
    // and never re-poisoned between graph replays). Tiny async fill, capturable.
    hipMemsetAsync(cnt, 0, sizeof(unsigned), stream);
    loss_main<<<NB, NT, 0, stream>>>(y_pred, eta, p_in, bbox, partial, cnt, out);
}

// Round 8
// 29.120 us; speedup vs baseline: 4.6469x; 4.6469x over previous
//
#include <hip/hip_runtime.h>

// Problem constants: BS=2048, P=32, C=14
constexpr int NB = 2048;
constexpr int NP = 32;
constexpr int NC = 14;
constexpr int ELEMS_PER_B = NP * NP * NC;   // 14336 floats per batch slice
constexpr int NT = 448;                      // 7 waves
constexpr int NITER = 8;                     // 448 threads * 4 floats * 8 iters = 14336
constexpr int STR = 132;                     // LDS channel stride; 132%32=4 -> banks rotate per channel

// Flat element f = it*1792 + 4*tid + k  (1792 = 14*128, channel-neutral per iter)
//   ch      = (4*tid+k) % 14      (constant per thread/k)
//   posBase = (4*tid+k) / 14      in [0,128)
//   pos     = it*128 + posBase ;  j = posBase&31 (const) ; i = 4*it + (posBase>>5)
// (ch, posBase) is a bijection over the 1792 thread-lane slots -> LDS [14][STR] reduction.
__global__ __launch_bounds__(NT) void loss_main(
    const float* __restrict__ y_pred,
    const float* __restrict__ eta,
    const float* __restrict__ p_in,
    const float* __restrict__ bbox,
    float* __restrict__ partial)
{
    const int b   = blockIdx.x;
    const int tid = threadIdx.x;

    __shared__ int   win[NC][4];             // x0, y0, x1, y1
    __shared__ float ep[2][NC];              // eta, p (prefetched early)
    __shared__ float rAll[NC * STR];
    __shared__ float r1[NC * STR];
    __shared__ float r3[NC * STR];
    __shared__ float lossArr[NC];

    if (tid < NC) {
        const float* bb = bbox + ((size_t)b * NC + tid) * 4;
        int x0 = (int)(bb[0] * (float)NP);   // trunc toward zero == astype(int32)
        int y0 = (int)(bb[1] * (float)NP);
        int w  = (int)(bb[2] * (float)NP);
        int h  = (int)(bb[3] * (float)NP);
        win[tid][0] = x0;
        win[tid][1] = y0;
        win[tid][2] = x0 + w;
        win[tid][3] = y0 + h;
        ep[0][tid] = eta[(size_t)b * NC + tid];
        ep[1][tid] = p_in[(size_t)b * NC + tid];
    }
    __syncthreads();

    int  ch[4], pB[4], ihi[4], ry0[4], ry1[4];
    bool col[4];
    #pragma unroll
    for (int k = 0; k < 4; ++k) {
        int f0 = 4 * tid + k;
        ch[k]  = f0 % NC;
        pB[k]  = f0 / NC;
        int j  = pB[k] & 31;
        ihi[k] = pB[k] >> 5;
        ry0[k] = win[ch[k]][1];
        ry1[k] = win[ch[k]][3];
        col[k] = (j >= win[ch[k]][0]) && (j < win[ch[k]][2]);
    }

    float aAll[4] = {1.f, 1.f, 1.f, 1.f};
    float a1[4]   = {1.f, 1.f, 1.f, 1.f};
    float a3[4]   = {1.f, 1.f, 1.f, 1.f};

    const float4* base = reinterpret_cast<const float4*>(y_pred + (size_t)b * ELEMS_PER_B);

    #pragma unroll
    for (int it = 0; it < NITER; ++it) {
        const float4 v = base[it * NT + tid];   // plain cached load (nt was a 6x loss)
        const float vv[4] = {v.x, v.y, v.z, v.w};
        #pragma unroll
        for (int k = 0; k < 4; ++k) {
            const int i = 4 * it + ihi[k];
            float yp0 = fminf(1.f, vv[k]);
            float t0  = fminf(1.f, 1.f - yp0);
            float yp  = fmaf(yp0, 0.02f, 0.98f);
            float t   = fmaf(t0,  0.02f, 0.98f);
            aAll[k] *= t;
            bool m = col[k] && (i >= ry0[k]) && (i < ry1[k]);
            a1[k] *= m ? yp : 1.f;
            a3[k] *= m ? t  : 1.f;
        }
    }

    #pragma unroll
    for (int k = 0; k < 4; ++k) {
        const int a = ch[k] * STR + pB[k];
        rAll[a] = aAll[k];
        r1[a]   = a1[k];
        r3[a]   = a3[k];
    }
    __syncthreads();

    // 7-step multiply tree over the 128 partials per channel
    #pragma unroll
    for (int s = 64; s >= 1; s >>= 1) {
        for (int idx = tid; idx < NC * s; idx += NT) {
            const int c = idx / s, m = idx - c * s;
            const int a = c * STR + m, a2 = a + s;
            rAll[a] *= rAll[a2];
            r1[a]   *= r1[a2];
            r3[a]   *= r3[a2];
        }
        __syncthreads();
    }

    if (tid < NC) {
        float Pall = rAll[tid * STR];        // prod of tmp over all (i,j)
        float P1   = r1[tid * STR];          // prod of yp inside bbox
        float P3   = r3[tid * STR];          // prod of tmp inside bbox
        float pyx  = 1.f - Pall;
        float pyxb = P1 * Pall / P3 + 1e-10f;
        float e  = ep[0][tid];
        float pp = ep[1][tid];
        float loss = -e * logf(pyxb)
                     - (1.f - e) * pp * logf(pyx)
                     - (1.f - e) * (1.f - pp) * logf(Pall);
        lossArr[tid] = loss;
    }
    __syncthreads();

    if (tid == 0) {
        float s = 0.f;
        #pragma unroll
        for (int c = 0; c < NC; ++c) s += lossArr[c];
        partial[b] = s;
    }
}

// Deterministic fixed-order final reduction; overwrites d_out.
__global__ __launch_bounds__(1024) void reduce_partials(
    const float* __restrict__ partial, float* __restrict__ out)
{
    __shared__ float s[1024];
    const int t = threadIdx.x;
    s[t] = partial[t] + partial[t + 1024];
    __syncthreads();
    for (int st = 512; st >= 1; st >>= 1) {
        if (t < st) s[t] += s[t + st];
        __syncthreads();
    }
    if (t == 0) out[0] = s[0] / (float)NB;
}

extern "C" void kernel_launch(void* const* d_in, const int* in_sizes, int n_in,
                              void* d_out, int out_size, void* d_ws, size_t ws_size,
                              hipStream_t stream)
{
    const float* y_pred = (const float*)d_in[0];
    const float* eta    = (const float*)d_in[1];
    const float* p_in   = (const float*)d_in[2];
    const float* bbox   = (const float*)d_in[3];
    float* partial = (float*)d_ws;           // 2048 floats = 8 KB scratch
    float* out     = (float*)d_out;

    loss_main<<<NB, NT, 0, stream>>>(y_pred, eta, p_in, bbox, partial);
    reduce_partials<<<1, 1024, 0, stream>>>(partial, out);
}

// Round 9
// 28.651 us; speedup vs baseline: 4.7230x; 1.0164x over previous
//
#include <hip/hip_runtime.h>

// Problem constants: BS=2048, P=32, C=14
constexpr int NB = 2048;
constexpr int NP = 32;
constexpr int NC = 14;
constexpr int ELEMS_PER_B = NP * NP * NC;   // 14336 floats per batch slice
constexpr int NT = 448;                      // 7 waves
constexpr int NITER = 8;                     // 448 threads * 4 floats * 8 iters = 14336
constexpr int STR = 132;                     // LDS channel stride; 132%32=4 -> banks rotate per channel
constexpr int PIPE = 4;                      // register-pipeline depth (16 VGPR of data)

// Flat element f = it*1792 + 4*tid + k  (1792 = 14*128, channel-neutral per iter)
//   ch      = (4*tid+k) % 14      (constant per thread/k)
//   posBase = (4*tid+k) / 14      in [0,128)
//   pos     = it*128 + posBase ;  j = posBase&31 (const) ; i = 4*it + (posBase>>5)
// (ch, posBase) is a bijection over the 1792 thread-lane slots -> LDS [14][STR] reduction.
__global__ __launch_bounds__(NT) void loss_main(
    const float* __restrict__ y_pred,
    const float* __restrict__ eta,
    const float* __restrict__ p_in,
    const float* __restrict__ bbox,
    float* __restrict__ partial)
{
    const int b   = blockIdx.x;
    const int tid = threadIdx.x;

    __shared__ int   win[NC][4];             // x0, y0, x1, y1
    __shared__ float ep[2][NC];              // eta, p (prefetched early)
    __shared__ float rAll[NC * STR];
    __shared__ float r1[NC * STR];
    __shared__ float r3[NC * STR];
    __shared__ float lossArr[NC];

    if (tid < NC) {
        const float* bb = bbox + ((size_t)b * NC + tid) * 4;
        int x0 = (int)(bb[0] * (float)NP);   // trunc toward zero == astype(int32)
        int y0 = (int)(bb[1] * (float)NP);
        int w  = (int)(bb[2] * (float)NP);
        int h  = (int)(bb[3] * (float)NP);
        win[tid][0] = x0;
        win[tid][1] = y0;
        win[tid][2] = x0 + w;
        win[tid][3] = y0 + h;
        ep[0][tid] = eta[(size_t)b * NC + tid];
        ep[1][tid] = p_in[(size_t)b * NC + tid];
    }
    __syncthreads();

    int  ch[4], pB[4], ihi[4], ry0[4], ry1[4];
    bool col[4];
    #pragma unroll
    for (int k = 0; k < 4; ++k) {
        int f0 = 4 * tid + k;
        ch[k]  = f0 % NC;
        pB[k]  = f0 / NC;
        int j  = pB[k] & 31;
        ihi[k] = pB[k] >> 5;
        ry0[k] = win[ch[k]][1];
        ry1[k] = win[ch[k]][3];
        col[k] = (j >= win[ch[k]][0]) && (j < win[ch[k]][2]);
    }

    float aAll[4] = {1.f, 1.f, 1.f, 1.f};
    float a1[4]   = {1.f, 1.f, 1.f, 1.f};
    float a3[4]   = {1.f, 1.f, 1.f, 1.f};

    const float4* base = reinterpret_cast<const float4*>(y_pred + (size_t)b * ELEMS_PER_B);

    // 4-deep register pipeline: keep 4 dwordx4 loads in flight per wave.
    float4 buf[PIPE];
    #pragma unroll
    for (int k = 0; k < PIPE; ++k) buf[k] = base[k * NT + tid];

    #pragma unroll
    for (int it = 0; it < NITER; ++it) {
        const float4 v = buf[it % PIPE];
        if (it + PIPE < NITER) buf[it % PIPE] = base[(it + PIPE) * NT + tid];
        const float vv[4] = {v.x, v.y, v.z, v.w};
        #pragma unroll
        for (int k = 0; k < 4; ++k) {
            const int i = 4 * it + ihi[k];
            float yp0 = fminf(1.f, vv[k]);
            float t0  = fminf(1.f, 1.f - yp0);
            float yp  = fmaf(yp0, 0.02f, 0.98f);
            float t   = fmaf(t0,  0.02f, 0.98f);
            aAll[k] *= t;
            bool m = col[k] && (i >= ry0[k]) && (i < ry1[k]);
            a1[k] *= m ? yp : 1.f;
            a3[k] *= m ? t  : 1.f;
        }
    }

    #pragma unroll
    for (int k = 0; k < 4; ++k) {
        const int a = ch[k] * STR + pB[k];
        rAll[a] = aAll[k];
        r1[a]   = a1[k];
        r3[a]   = a3[k];
    }
    __syncthreads();

    // 7-step multiply tree over the 128 partials per channel
    #pragma unroll
    for (int s = 64; s >= 1; s >>= 1) {
        for (int idx = tid; idx < NC * s; idx += NT) {
            const int c = idx / s, m = idx - c * s;
            const int a = c * STR + m, a2 = a + s;
            rAll[a] *= rAll[a2];
            r1[a]   *= r1[a2];
            r3[a]   *= r3[a2];
        }
        __syncthreads();
    }

    if (tid < NC) {
        float Pall = rAll[tid * STR];        // prod of tmp over all (i,j)
        float P1   = r1[tid * STR];          // prod of yp inside bbox
        float P3   = r3[tid * STR];          // prod of tmp inside bbox
        float pyx  = 1.f - Pall;
        float pyxb = P1 * Pall / P3 + 1e-10f;
        float e  = ep[0][tid];
        float pp = ep[1][tid];
        float loss = -e * logf(pyxb)
                     - (1.f - e) * pp * logf(pyx)
                     - (1.f - e) * (1.f - pp) * logf(Pall);
        lossArr[tid] = loss;
    }
    __syncthreads();

    if (tid == 0) {
        float s = 0.f;
        #pragma unroll
        for (int c = 0; c < NC; ++c) s += lossArr[c];
        partial[b] = s;
    }
}

// Deterministic final reduction, minimal-latency tail:
// 256 threads x 2 float4 loads, 6-step shuffle tree, one barrier.
__global__ __launch_bounds__(256) void reduce_partials(
    const float* __restrict__ partial, float* __restrict__ out)
{
    __shared__ float waveS[4];
    const int t = threadIdx.x;
    const float4* p4 = reinterpret_cast<const float4*>(partial);
    float4 a = p4[t];            // elements 4t .. 4t+3
    float4 c = p4[t + 256];      // elements 1024+4t ..
    float acc = (a.x + a.y) + (a.z + a.w) + (c.x + c.y) + (c.z + c.w);
    #pragma unroll
    for (int off = 32; off >= 1; off >>= 1)
        acc += __shfl_xor(acc, off);
    if ((t & 63) == 0) waveS[t >> 6] = acc;
    __syncthreads();
    if (t == 0)
        out[0] = ((waveS[0] + waveS[1]) + (waveS[2] + waveS[3])) / (float)NB;
}

extern "C" void kernel_launch(void* const* d_in, const int* in_sizes, int n_in,
                              void* d_out, int out_size, void* d_ws, size_t ws_size,
                              hipStream_t stream)
{
    const float* y_pred = (const float*)d_in[0];
    const float* eta    = (const float*)d_in[1];
    const float* p_in   = (const float*)d_in[2];
    const float* bbox   = (const float*)d_in[3];
    float* partial = (float*)d_ws;           // 2048 floats = 8 KB scratch
    float* out     = (float*)d_out;

    loss_main<<<NB, NT, 0, stream>>>(y_pred, eta, p_in, bbox, partial);
    reduce_partials<<<1, 256, 0, stream>>>(partial, out);
}